// Round 15
// baseline (723.623 us; speedup 1.0000x reference)
//
#include <hip/hip_runtime.h>
#include <hip/hip_bf16.h>
#include <stdint.h>

#define S_LEN 2048
#define D_MODEL 2048
#define NH 16
#define HD_DIM 128
#define BATCH 4

typedef unsigned short u16;
typedef unsigned int u32;
typedef short s16x8 __attribute__((ext_vector_type(8)));
typedef float f32x4 __attribute__((ext_vector_type(4)));

__device__ __forceinline__ u16 f2b(float f) {
    union { float f; u32 u; } v; v.f = f;
    u32 r = v.u + 0x7FFFu + ((v.u >> 16) & 1u);
    return (u16)(r >> 16);
}

__device__ __forceinline__ u32 cvtpk(float lo, float hi) {
    u32 r;
    asm("v_cvt_pk_bf16_f32 %0, %1, %2" : "=v"(r) : "v"(lo), "v"(hi));
    return r;
}

// pure (non-volatile) single-instruction helpers — schedulable/CSE-able
__device__ __forceinline__ float exp2a(float x) {
    float r;
    asm("v_exp_f32 %0, %1" : "=v"(r) : "v"(x));
    return r;
}
__device__ __forceinline__ float max3a(float a, float b, float c) {
    float r;
    asm("v_max3_f32 %0, %1, %2, %3" : "=v"(r) : "v"(a), "v"(b), "v"(c));
    return r;
}

#define L2E 1.4426950408889634f

#define BAR()   asm volatile("s_barrier" ::: "memory")
#define LGKM0() asm volatile("s_waitcnt lgkmcnt(0)" ::: "memory")
#define VMW(n)  asm volatile("s_waitcnt vmcnt(" #n ")" ::: "memory")

// all 4 weight matrices in one launch (dsts are contiguous in ws)
__global__ __launch_bounds__(256) void cvt_w4(const float* __restrict__ s0,
                                              const float* __restrict__ s1,
                                              const float* __restrict__ s2,
                                              const float* __restrict__ s3,
                                              u16* __restrict__ out) {
    int i = blockIdx.x * 256 + threadIdx.x;          // i in [0, 4*524288)
    const int seg = i >> 19, li = i & 524287;
    const float* s = (seg == 0) ? s0 : (seg == 1) ? s1 : (seg == 2) ? s2 : s3;
    const float4* p = reinterpret_cast<const float4*>(s) + (size_t)li * 2;
    float4 a = p[0], b = p[1];
    s16x8 o;
    o[0] = (short)f2b(a.x); o[1] = (short)f2b(a.y);
    o[2] = (short)f2b(a.z); o[3] = (short)f2b(a.w);
    o[4] = (short)f2b(b.x); o[5] = (short)f2b(b.y);
    o[6] = (short)f2b(b.z); o[7] = (short)f2b(b.w);
    *(reinterpret_cast<s16x8*>(out) + i) = o;
}

// ---------------- 256x256 8-phase NT GEMM: C = alpha * A[M,K] @ B[N,K]^T ----------------
// A_F32 = 1: A operand is fp32 in global, converted in-kernel (fused cvt):
//   issue-early/write-late reg staging — fp32 loads for tile t+1 issued at p0/p1
//   (latency hidden under QUADs), cvt_pk + ds_write at p2/p3; ds_writes published
//   by LGKM0 before the tile-end barrier; B-only gload_lds drained by VMW(0).
// A_F32 = 0: proven bf16 gload_lds path (round-4 ledger, unchanged).
// OUT_F32: 0 = bf16 C, 1 = f32 C.
template<int A_F32, int OUT_F32>
__global__ __launch_bounds__(512, 1) void gemm256(const void* __restrict__ Av,
                                                  const u16* __restrict__ Bw,
                                                  void* __restrict__ Cv,
                                                  int M, int N, int K, float alpha) {
    __shared__ u16 lds[2][2][256 * 64];
    const int t = threadIdx.x, lane = t & 63, w = t >> 6;
    const int wm = w >> 2, wn = w & 3;
    const int lr = lane & 15, lk = lane >> 4;
    const int NT = K >> 6;

    const u16* Ab = (const u16*)Av;
    const float* Af = (const float*)Av;

    // bijective XCD swizzle (gridDim.x % 8 == 0 for all launches here)
    const int ntile = N >> 8;
    int flat = blockIdx.x;
    int cpx = gridDim.x >> 3;
    int rmap = (flat & 7) * cpx + (flat >> 3);
    const int m0 = (rmap / ntile) * 256, n0 = (rmap % ntile) * 256;

    // staging constants: thread covers row q*64 + (t>>3), position chunk t&7
    const int srow = t >> 3;
    const int spos = t & 7;
    const int scon = spos ^ (srow & 7);   // content chunk (pre-swizzled source)

    auto stage = [&](const u16* gbase, int grow0, int ldsT, int buf, int q, int kt) {
        const u16* src = gbase + (size_t)(grow0 + q * 64 + srow) * K + kt * 64 + scon * 8;
        u16* dst = &lds[buf][ldsT][(q * 64 + srow) * 64 + spos * 8];
        __builtin_amdgcn_global_load_lds(
            (const __attribute__((address_space(1))) void*)src,
            (__attribute__((address_space(3))) void*)dst, 16, 0, 0);
    };

    // fp32-A reg staging state (A_F32 path): 8 float4 live across 2 phases
    f32x4 areg[4][2];
    auto loadA = [&](int q, int kt) {
        const float* src = Af + (size_t)(m0 + q * 64 + srow) * K + kt * 64 + scon * 8;
        areg[q][0] = *(const f32x4*)(src);
        areg[q][1] = *(const f32x4*)(src + 4);
    };
    auto writeA = [&](int buf, int q) {
        union { s16x8 v; u32 u[4]; } o;
        o.u[0] = cvtpk(areg[q][0][0], areg[q][0][1]);
        o.u[1] = cvtpk(areg[q][0][2], areg[q][0][3]);
        o.u[2] = cvtpk(areg[q][1][0], areg[q][1][1]);
        o.u[3] = cvtpk(areg[q][1][2], areg[q][1][3]);
        *(s16x8*)(&lds[buf][0][(q * 64 + srow) * 64 + spos * 8]) = o.v;
    };

    f32x4 acc[8][4];
#pragma unroll
    for (int i = 0; i < 8; ++i)
#pragma unroll
        for (int j = 0; j < 4; ++j) acc[i][j] = {0.f, 0.f, 0.f, 0.f};

    s16x8 a[4][2], b[4][2];

    // prologue: tile 0
    if constexpr (A_F32) {
        stage(Bw, n0, 1, 0, 0, 0);
        stage(Bw, n0, 1, 0, 1, 0);
        stage(Bw, n0, 1, 0, 2, 0);
        stage(Bw, n0, 1, 0, 3, 0);
        loadA(0, 0); loadA(1, 0); loadA(2, 0); loadA(3, 0);
        writeA(0, 0); writeA(0, 1); writeA(0, 2); writeA(0, 3);
        VMW(0);
        LGKM0();
        BAR();
    } else {
        stage(Bw, n0, 1, 0, 0, 0);
        stage(Bw, n0, 1, 0, 1, 0);
        stage(Bw, n0, 1, 0, 2, 0);
        stage(Bw, n0, 1, 0, 3, 0);
        stage(Ab, m0, 0, 0, 0, 0);
        stage(Ab, m0, 0, 0, 2, 0);
        stage(Ab, m0, 0, 0, 1, 0);
        stage(Ab, m0, 0, 0, 3, 0);
        VMW(2);
        BAR();
    }

#define LDFRAG(base, row, kk) \
    (*(const s16x8*)((base) + (row) * 64 + ((((kk) * 4 + lk) ^ (lr & 7)) << 3)))

#define QUAD(mh, nh)                                                                   \
    __builtin_amdgcn_s_setprio(1);                                                     \
    _Pragma("unroll")                                                                  \
    for (int mf = 0; mf < 4; ++mf)                                                     \
        _Pragma("unroll")                                                              \
        for (int nf = 0; nf < 2; ++nf)                                                 \
            _Pragma("unroll")                                                          \
            for (int kk = 0; kk < 2; ++kk)                                             \
                acc[(mh) * 4 + mf][(nh) * 2 + nf] = __builtin_amdgcn_mfma_f32_16x16x32_bf16( \
                    a[mf][kk], b[(nh) * 2 + nf][kk], acc[(mh) * 4 + mf][(nh) * 2 + nf], 0, 0, 0); \
    __builtin_amdgcn_s_setprio(0);

    for (int kt = 0; kt < NT; ++kt) {
        const int buf = kt & 1;
        const u16* la = &lds[buf][0][0];
        const u16* lb = &lds[buf][1][0];
        const int nx = kt + 1;
        const bool st = nx < NT;

        // ---- phase 0: quadrant (0,0) ----
#pragma unroll
        for (int mf = 0; mf < 4; ++mf)
#pragma unroll
            for (int kk = 0; kk < 2; ++kk)
                a[mf][kk] = LDFRAG(la, wm * 128 + mf * 16 + lr, kk);
#pragma unroll
        for (int nf = 0; nf < 2; ++nf)
#pragma unroll
            for (int kk = 0; kk < 2; ++kk)
                b[nf][kk] = LDFRAG(lb, wn * 64 + nf * 16 + lr, kk);
        if (st) {
            if constexpr (A_F32) { loadA(0, nx); loadA(1, nx); }
            stage(Bw, n0, 1, buf ^ 1, 0, nx);
            stage(Bw, n0, 1, buf ^ 1, 1, nx);
        }
        BAR();
        LGKM0();
        QUAD(0, 0);
        BAR();

        // ---- phase 1: quadrant (0,1) ----
#pragma unroll
        for (int nf = 2; nf < 4; ++nf)
#pragma unroll
            for (int kk = 0; kk < 2; ++kk)
                b[nf][kk] = LDFRAG(lb, wn * 64 + nf * 16 + lr, kk);
        if (st) {
            if constexpr (A_F32) { loadA(2, nx); loadA(3, nx); }
            stage(Bw, n0, 1, buf ^ 1, 2, nx);
            stage(Bw, n0, 1, buf ^ 1, 3, nx);
        }
        BAR();
        LGKM0();
        QUAD(0, 1);
        if constexpr (!A_F32) {
            if (kt == NT - 1) { VMW(0); } else { VMW(4); }
        }
        BAR();

        // ---- phase 2: quadrant (1,0) ----
#pragma unroll
        for (int mf = 0; mf < 4; ++mf)
#pragma unroll
            for (int kk = 0; kk < 2; ++kk)
                a[mf][kk] = LDFRAG(la, wm * 128 + 64 + mf * 16 + lr, kk);
        if (st) {
            if constexpr (A_F32) { writeA(buf ^ 1, 0); writeA(buf ^ 1, 1); }
            else { stage(Ab, m0, 0, buf ^ 1, 0, nx); stage(Ab, m0, 0, buf ^ 1, 2, nx); }
        }
        BAR();
        LGKM0();
        QUAD(1, 0);
        BAR();

        // ---- phase 3: quadrant (1,1) ----
        if (st) {
            if constexpr (A_F32) { writeA(buf ^ 1, 2); writeA(buf ^ 1, 3); }
            else { stage(Ab, m0, 0, buf ^ 1, 1, nx); stage(Ab, m0, 0, buf ^ 1, 3, nx); }
        }
        BAR();
        QUAD(1, 1);
        if constexpr (A_F32) {
            LGKM0();   // publish this tile's A ds_writes (p2 + p3) before swap
            VMW(0);    // drain the 4 B gload_lds for tile nx
        } else {
            VMW(2);
        }
        BAR();
    }

    // epilogue: C layout col = lr, row = lk*4 + reg
#pragma unroll
    for (int i = 0; i < 8; ++i)
#pragma unroll
        for (int j = 0; j < 4; ++j) {
            int r0 = m0 + wm * 128 + (i >> 2) * 64 + (i & 3) * 16 + lk * 4;
            int c0 = n0 + wn * 64 + j * 16 + lr;
            if constexpr (OUT_F32) {
                float* C = (float*)Cv;
#pragma unroll
                for (int r = 0; r < 4; ++r) C[(size_t)(r0 + r) * N + c0] = acc[i][j][r] * alpha;
            } else {
                u16* C = (u16*)Cv;
#pragma unroll
                for (int r = 0; r < 4; ++r) C[(size_t)(r0 + r) * N + c0] = f2b(acc[i][j][r] * alpha);
            }
        }
}

// ---------------- flash attention (round-14 winner, unchanged) ----------------
__global__ __launch_bounds__(512, 2) void attn_kernel(
    const u16* __restrict__ Qh, const u16* __restrict__ Kh, const u16* __restrict__ Vh,
    const float* __restrict__ mask, const float* __restrict__ kpad,
    u16* __restrict__ Comb) {
    __shared__ u16 Ks[2][64 * 128];
    __shared__ u16 Vt[2][128 * 64];

    const int t = threadIdx.x, lane = t & 63, w = t >> 6;   // w: 0..7
    const int lr = lane & 15, lk = lane >> 4;

    const int g = blockIdx.x;
    const int rm = (g & 7) * 64 + (g >> 3);      // 512 % 8 == 0: bijective
    const int qb = rm & 7, h = (rm >> 3) & 15, b = rm >> 7;  // qb fast (L3-friendly)
    const int q0w = qb * 256 + w * 32;
    const size_t rowBase = (size_t)b * S_LEN;
    const u16* Kb = Kh + rowBase * D_MODEL + h * HD_DIM;
    const u16* Vb = Vh + rowBase * D_MODEL + h * HD_DIM;

    // Q fragments (B operand): q = q0w + qi*16 + lr, d = dc*32 + lk*8 + j.
    // (scale*log2e pre-folded into the Q projection)
    s16x8 qf[2][4];
#pragma unroll
    for (int qi = 0; qi < 2; ++qi)
#pragma unroll
        for (int dc = 0; dc < 4; ++dc)
            qf[qi][dc] = *(const s16x8*)(Qh + (rowBase + q0w + qi * 16 + lr) * D_MODEL +
                                         h * HD_DIM + dc * 32 + lk * 8);

    f32x4 o[2][8];
#pragma unroll
    for (int qi = 0; qi < 2; ++qi)
#pragma unroll
        for (int dt = 0; dt < 8; ++dt) o[qi][dt] = {0.f, 0.f, 0.f, 0.f};
    float m_[2] = {-3e38f, -3e38f}, l_[2] = {0.f, 0.f};

    // K staging (512 threads, 2 passes of 32 rows)
    const int ksub = t >> 4;                          // 0..31
    const int kchunk = (t & 15) ^ (ksub & 7);         // pre-swizzled global chunk
    // V staging (512 threads, one pass covers all 64 kv rows)
    const int vrow = t >> 3;                          // 0..63
    const int vc0 = (t & 7) * 16;
    const int vodd = vrow & 1;
    const int vp = t >> 4;                            // kv-pair 0..31

    s16x8 va0, va1;

    auto stageK = [&](int kv0, int nb) {
#pragma unroll
        for (int p = 0; p < 2; ++p) {
            const u16* src = Kb + (size_t)(kv0 + p * 32 + ksub) * D_MODEL + kchunk * 8;
            __builtin_amdgcn_global_load_lds(
                (const __attribute__((address_space(1))) void*)src,
                (__attribute__((address_space(3))) void*)(&Ks[nb][p * 4096 + t * 8]), 16, 0, 0);
        }
    };
    auto loadV = [&](int kv0) {
        const u16* p0 = Vb + (size_t)(kv0 + vrow) * D_MODEL + vc0;
        va0 = *(const s16x8*)p0;
        va1 = *(const s16x8*)(p0 + 8);
    };
    auto writeV = [&](int nb) {
        union VU { s16x8 v[2]; u32 uw[8]; u16 us[16]; };
        VU A;
        A.v[0] = va0; A.v[1] = va1;
        u32 ra[4];
#pragma unroll
        for (int i = 0; i < 4; ++i)
            ra[i] = (u32)__shfl_xor((int)(vodd ? A.uw[i] : A.uw[i + 4]), 8, 64);
#pragma unroll
        for (int e = 0; e < 8; ++e) {
            int d = vc0 + vodd * 8 + e;
            int swz = ((d >> 4) ^ (d & 7)) & 7;
            u16 rau = (u16)((ra[e >> 1] >> ((e & 1) * 16)) & 0xffff);
            u16 lo1, hi1;
            if (vodd) { lo1 = rau; hi1 = A.us[8 + e]; }
            else      { lo1 = A.us[e]; hi1 = rau; }
            int c1 = (vp >> 2) ^ swz;
            *(u32*)(&Vt[nb][d * 64 + c1 * 8 + (vp & 3) * 2]) = (u32)lo1 | ((u32)hi1 << 16);
        }
    };

    // mask/kpad register prefetch (one tile ahead)
    f32x4 mreg[2][4], kreg[4];
    auto loadMask = [&](int kv0) {
#pragma unroll
        for (int qi = 0; qi < 2; ++qi) {
            const float* mrow = mask + (size_t)(q0w + qi * 16 + lr) * S_LEN + kv0;
#pragma unroll
            for (int kt = 0; kt < 4; ++kt)
                mreg[qi][kt] = *(const f32x4*)(mrow + kt * 16 + lk * 4);
        }
#pragma unroll
        for (int kt = 0; kt < 4; ++kt)
            kreg[kt] = *(const f32x4*)(kpad + b * S_LEN + kv0 + kt * 16 + lk * 4);
    };

    // prologue: stage tile 0 (full drain once)
    stageK(0, 0);
    loadV(0);
    writeV(0);
    loadMask(0);
    __syncthreads();

    const int srcA = ((lk & 1) * 32) + lr;   // lane holding lk' = (lk&1)*2
    const int srcB = srcA + 16;

    for (int i = 0; i < 32; ++i) {
        const int cur = i & 1;
        const u16* ks = &Ks[cur][0];
        const u16* vt = &Vt[cur][0];
        const int kv0 = i * 64;

        if (i < 31) { stageK(kv0 + 64, cur ^ 1); loadV(kv0 + 64); }

        // QK^T (swapped): sc[qi][kt]: lane holds S[kv=kt*16+lk*4+r][q=qi*16+lr]
        f32x4 sc[2][4];
#pragma unroll
        for (int qi = 0; qi < 2; ++qi)
#pragma unroll
            for (int kt = 0; kt < 4; ++kt) sc[qi][kt] = {0.f, 0.f, 0.f, 0.f};
        __builtin_amdgcn_s_setprio(1);
#pragma unroll
        for (int kt = 0; kt < 4; ++kt) {
            s16x8 kf[4];
#pragma unroll
            for (int dc = 0; dc < 4; ++dc)
                kf[dc] = *(const s16x8*)(&ks[(kt * 16 + lr) * 128 +
                                             (((dc * 4 + lk) ^ (lr & 7)) << 3)]);
#pragma unroll
            for (int dc = 0; dc < 4; ++dc) {
                sc[0][kt] = __builtin_amdgcn_mfma_f32_16x16x32_bf16(kf[dc], qf[0][dc], sc[0][kt], 0, 0, 0);
                sc[1][kt] = __builtin_amdgcn_mfma_f32_16x16x32_bf16(kf[dc], qf[1][dc], sc[1][kt], 0, 0, 0);
            }
        }
        __builtin_amdgcn_s_setprio(0);

        // masks (prefetched regs, folded *log2e via fma) + online softmax (log2 domain)
        u32 lo[2][4], hi[2][4];
#pragma unroll
        for (int qi = 0; qi < 2; ++qi) {
            float s[16];
#pragma unroll
            for (int kt = 0; kt < 4; ++kt)
#pragma unroll
                for (int r = 0; r < 4; ++r)
                    s[kt * 4 + r] = fmaf(mreg[qi][kt][r], L2E,
                                         fmaf(kreg[kt][r], L2E, sc[qi][kt][r]));
            float t0 = max3a(s[0], s[1], s[2]);
            float t1 = max3a(s[3], s[4], s[5]);
            float t2 = max3a(s[6], s[7], s[8]);
            float t3 = max3a(s[9], s[10], s[11]);
            float t4 = max3a(s[12], s[13], s[14]);
            float mx = fmaxf(max3a(t0, t1, t2), max3a(t3, t4, s[15]));
            mx = fmaxf(mx, __shfl_xor(mx, 16, 64));
            mx = fmaxf(mx, __shfl_xor(mx, 32, 64));
            // defer-max (T13): 11.5 log2-units ~= 8 e-units
            if (__any(mx > m_[qi] + 11.5f)) {
                float mn = fmaxf(m_[qi], mx);
                float fs = exp2a(m_[qi] - mn);
                m_[qi] = mn;
                l_[qi] *= fs;
#pragma unroll
                for (int r = 0; r < 4; ++r) {
                    float fsb = __shfl(fs, (lane & 48) | (lk * 4 + r), 64);
#pragma unroll
                    for (int dt = 0; dt < 8; ++dt) o[qi][dt][r] *= fsb;
                }
            }
            float ls = 0.f;
#pragma unroll
            for (int e = 0; e < 16; ++e) { s[e] = exp2a(s[e] - m_[qi]); ls += s[e]; }
            ls += __shfl_xor(ls, 16, 64);
            ls += __shfl_xor(ls, 32, 64);
            l_[qi] += ls;
#pragma unroll
            for (int kt = 0; kt < 4; ++kt) {
                lo[qi][kt] = cvtpk(s[kt * 4 + 0], s[kt * 4 + 1]);
                hi[qi][kt] = cvtpk(s[kt * 4 + 2], s[kt * 4 + 3]);
            }
        }

        // prefetch next tile's mask/kpad (regs free after s[] computed above)
        if (i < 31) loadMask(kv0 + 64);

        // redistribute P (C-layout) -> A-frag in-register
        s16x8 pf[2][2];
        const bool sel = (lk >> 1) & 1;
#pragma unroll
        for (int qi = 0; qi < 2; ++qi)
#pragma unroll
            for (int hh = 0; hh < 2; ++hh) {
                u32 w0a = (u32)__shfl((int)lo[qi][2 * hh], srcA, 64);
                u32 w0b = (u32)__shfl((int)lo[qi][2 * hh + 1], srcA, 64);
                u32 w1a = (u32)__shfl((int)hi[qi][2 * hh], srcA, 64);
                u32 w1b = (u32)__shfl((int)hi[qi][2 * hh + 1], srcA, 64);
                u32 w2a = (u32)__shfl((int)lo[qi][2 * hh], srcB, 64);
                u32 w2b = (u32)__shfl((int)lo[qi][2 * hh + 1], srcB, 64);
                u32 w3a = (u32)__shfl((int)hi[qi][2 * hh], srcB, 64);
                u32 w3b = (u32)__shfl((int)hi[qi][2 * hh + 1], srcB, 64);
                union { s16x8 v; u32 u[4]; } P;
                P.u[0] = sel ? w0b : w0a;
                P.u[1] = sel ? w1b : w1a;
                P.u[2] = sel ? w2b : w2a;
                P.u[3] = sel ? w3b : w3a;
                pf[qi][hh] = P.v;
            }

        // PV: o[qi][dt] += P[16x64] @ V[64x16]
        __builtin_amdgcn_s_setprio(1);
#pragma unroll
        for (int dt = 0; dt < 8; ++dt) {
            int swz = dt ^ (lr & 7);
            s16x8 vf0 = *(const s16x8*)(&vt[(dt * 16 + lr) * 64 + ((lk ^ swz) << 3)]);
            s16x8 vf1 = *(const s16x8*)(&vt[(dt * 16 + lr) * 64 + (((4 + lk) ^ swz) << 3)]);
            o[0][dt] = __builtin_amdgcn_mfma_f32_16x16x32_bf16(pf[0][0], vf0, o[0][dt], 0, 0, 0);
            o[1][dt] = __builtin_amdgcn_mfma_f32_16x16x32_bf16(pf[1][0], vf0, o[1][dt], 0, 0, 0);
            o[0][dt] = __builtin_amdgcn_mfma_f32_16x16x32_bf16(pf[0][1], vf1, o[0][dt], 0, 0, 0);
            o[1][dt] = __builtin_amdgcn_mfma_f32_16x16x32_bf16(pf[1][1], vf1, o[1][dt], 0, 0, 0);
        }
        __builtin_amdgcn_s_setprio(0);

        if (i < 31) writeV(cur ^ 1);
        LGKM0();
        BAR();
    }

    // epilogue: O = o / l; o C-layout: q = qi*16 + lk*4 + r, d = dt*16 + lr
#pragma unroll
    for (int qi = 0; qi < 2; ++qi)
#pragma unroll
        for (int r = 0; r < 4; ++r) {
            float lb = __shfl(l_[qi], (lane & 48) | (lk * 4 + r), 64);
            float inv = 1.0f / lb;
            size_t row = rowBase + q0w + qi * 16 + lk * 4 + r;
            u16* dst = Comb + row * D_MODEL + h * HD_DIM + lr;
#pragma unroll
            for (int dt = 0; dt < 8; ++dt) dst[dt * 16] = f2b(o[qi][dt][r] * inv);
        }
}

extern "C" void kernel_launch(void* const* d_in, const int* in_sizes, int n_in,
                              void* d_out, int out_size, void* d_ws, size_t ws_size,
                              hipStream_t stream) {
    const float* q    = (const float*)d_in[0];
    const float* k    = (const float*)d_in[1];
    const float* v    = (const float*)d_in[2];
    const float* mask = (const float*)d_in[3];
    const float* kpad = (const float*)d_in[4];
    const float* wq   = (const float*)d_in[5];
    const float* wk   = (const float*)d_in[6];
    const float* wv   = (const float*)d_in[7];
    const float* wo   = (const float*)d_in[8];
    float* out = (float*)d_out;

    u16* wqb  = (u16*)d_ws;                 // 2048*2048 bf16 each, contiguous x4
    u16* wkb  = wqb + 4194304;
    u16* wvb  = wkb + 4194304;
    u16* wob  = wvb + 4194304;
    u16* qh   = wob + 4194304;              // 8192*2048 bf16 each
    u16* kh   = qh + 16777216;
    u16* vh   = kh + 16777216;
    u16* comb = vh + 16777216;              // attn output (bf16)
    // total: 160 MB

    // 1/sqrt(128) * log2(e): Q-projection alpha puts QK^T scores in log2 domain
    const float scale = 0.08838834764831845f * 1.4426950408889634f;

    {
        int n8w = 4 * 524288;                // all 4 weight matrices, one launch
        dim3 gw((n8w + 255) / 256);
        cvt_w4<<<gw, 256, 0, stream>>>(wq, wk, wv, wo, wqb);
    }
    dim3 gg((8192 / 256) * (2048 / 256));   // 256 blocks

    // projections: fused fp32->bf16 A-path (no separate cvt kernels)
    gemm256<1, 0><<<gg, 512, 0, stream>>>(q, wqb, qh, 8192, 2048, 2048, scale);
    gemm256<1, 0><<<gg, 512, 0, stream>>>(k, wkb, kh, 8192, 2048, 2048, 1.0f);
    gemm256<1, 0><<<gg, 512, 0, stream>>>(v, wvb, vh, 8192, 2048, 2048, 1.0f);

    attn_kernel<<<dim3(512), 512, 0, stream>>>(qh, kh, vh, mask, kpad, comb);

    gemm256<0, 1><<<gg, 512, 0, stream>>>(comb, wob, out, 8192, 2048, 2048, 1.0f);
}

// Round 16
// 567.848 us; speedup vs baseline: 1.2743x; 1.2743x over previous
//
#include <hip/hip_runtime.h>
#include <hip/hip_bf16.h>
#include <stdint.h>

#define S_LEN 2048
#define D_MODEL 2048
#define NH 16
#define HD_DIM 128
#define BATCH 4

typedef unsigned short u16;
typedef unsigned int u32;
typedef short s16x8 __attribute__((ext_vector_type(8)));
typedef float f32x4 __attribute__((ext_vector_type(4)));

__device__ __forceinline__ u16 f2b(float f) {
    union { float f; u32 u; } v; v.f = f;
    u32 r = v.u + 0x7FFFu + ((v.u >> 16) & 1u);
    return (u16)(r >> 16);
}

__device__ __forceinline__ u32 cvtpk(float lo, float hi) {
    u32 r;
    asm("v_cvt_pk_bf16_f32 %0, %1, %2" : "=v"(r) : "v"(lo), "v"(hi));
    return r;
}

// pure (non-volatile) single-instruction helpers — schedulable/CSE-able
__device__ __forceinline__ float exp2a(float x) {
    float r;
    asm("v_exp_f32 %0, %1" : "=v"(r) : "v"(x));
    return r;
}
__device__ __forceinline__ float max3a(float a, float b, float c) {
    float r;
    asm("v_max3_f32 %0, %1, %2, %3" : "=v"(r) : "v"(a), "v"(b), "v"(c));
    return r;
}

#define L2E 1.4426950408889634f

#define BAR()   asm volatile("s_barrier" ::: "memory")
#define LGKM0() asm volatile("s_waitcnt lgkmcnt(0)" ::: "memory")
#define VMW(n)  asm volatile("s_waitcnt vmcnt(" #n ")" ::: "memory")

// ---------------- single fused fp32->bf16 conversion launch ----------------
// Converts all 4 weight matrices (-> wqb, contiguous) AND q,k,v activations.
// Activation dsts are chained into soon-to-be-overwritten GEMM buffers
// (q->kh, k->vh, v->comb): at every later step read-buf != write-buf, so no
// extra workspace is needed and all cvts collapse into ONE launch.
__global__ __launch_bounds__(256) void cvt_all(
    const float* __restrict__ wq, const float* __restrict__ wk,
    const float* __restrict__ wv, const float* __restrict__ wo,
    const float* __restrict__ q,  const float* __restrict__ k,
    const float* __restrict__ v,
    u16* __restrict__ wdst, u16* __restrict__ qdst,
    u16* __restrict__ kdst, u16* __restrict__ vdst) {
    int i = blockIdx.x * 256 + threadIdx.x;          // [0, 8388608)
    const float* src;
    u16* dst;
    if (i < 2097152) {                                // weights: 4 x 524288 n8-units
        const int seg = i >> 19, li = i & 524287;
        src = ((seg == 0) ? wq : (seg == 1) ? wk : (seg == 2) ? wv : wo) + (size_t)li * 8;
        dst = wdst + (size_t)i * 8;
    } else {                                          // activations: 3 x 2097152
        const int j = i - 2097152;
        const int seg = j >> 21, li = j & 2097151;
        src = ((seg == 0) ? q : (seg == 1) ? k : v) + (size_t)li * 8;
        dst = ((seg == 0) ? qdst : (seg == 1) ? kdst : vdst) + (size_t)li * 8;
    }
    const float4* p = reinterpret_cast<const float4*>(src);
    float4 a = p[0], b = p[1];
    s16x8 o;
    o[0] = (short)f2b(a.x); o[1] = (short)f2b(a.y);
    o[2] = (short)f2b(a.z); o[3] = (short)f2b(a.w);
    o[4] = (short)f2b(b.x); o[5] = (short)f2b(b.y);
    o[6] = (short)f2b(b.z); o[7] = (short)f2b(b.w);
    *reinterpret_cast<s16x8*>(dst) = o;
}

// ---------------- 256x256 8-phase NT GEMM: C = alpha * A[M,K] @ B[N,K]^T ----------------
// Proven round-13/14 kernel (bf16 gload_lds A+B, counted vmcnt ledger).
// OUT_MODE: 0 = bf16 row-major C[M,N]; 1 = f32 row-major.
template<int OUT_MODE>
__global__ __launch_bounds__(512, 1) void gemm256(const u16* __restrict__ Ab,
                                                  const u16* __restrict__ Bw,
                                                  void* __restrict__ Cv,
                                                  int M, int N, int K, float alpha) {
    __shared__ u16 lds[2][2][256 * 64];
    const int t = threadIdx.x, lane = t & 63, w = t >> 6;
    const int wm = w >> 2, wn = w & 3;
    const int lr = lane & 15, lk = lane >> 4;
    const int NT = K >> 6;

    // bijective XCD swizzle (gridDim.x % 8 == 0 for all launches here)
    const int ntile = N >> 8;
    int flat = blockIdx.x;
    int cpx = gridDim.x >> 3;
    int rmap = (flat & 7) * cpx + (flat >> 3);
    const int m0 = (rmap / ntile) * 256, n0 = (rmap % ntile) * 256;

    // staging constants: thread covers row q*64 + (t>>3), position chunk t&7
    const int srow = t >> 3;
    const int spos = t & 7;
    const int scon = spos ^ (srow & 7);   // content chunk (pre-swizzled source)

    auto stage = [&](const u16* gbase, int grow0, int ldsT, int buf, int q, int kt) {
        const u16* src = gbase + (size_t)(grow0 + q * 64 + srow) * K + kt * 64 + scon * 8;
        u16* dst = &lds[buf][ldsT][(q * 64 + srow) * 64 + spos * 8];
        __builtin_amdgcn_global_load_lds(
            (const __attribute__((address_space(1))) void*)src,
            (__attribute__((address_space(3))) void*)dst, 16, 0, 0);
    };

    f32x4 acc[8][4];
#pragma unroll
    for (int i = 0; i < 8; ++i)
#pragma unroll
        for (int j = 0; j < 4; ++j) acc[i][j] = {0.f, 0.f, 0.f, 0.f};

    s16x8 a[4][2], b[4][2];

    // prologue: tile 0, order BQ0-3, AQ0, AQ2, AQ1, AQ3 (A-upper last)
    stage(Bw, n0, 1, 0, 0, 0);
    stage(Bw, n0, 1, 0, 1, 0);
    stage(Bw, n0, 1, 0, 2, 0);
    stage(Bw, n0, 1, 0, 3, 0);
    stage(Ab, m0, 0, 0, 0, 0);
    stage(Ab, m0, 0, 0, 2, 0);
    stage(Ab, m0, 0, 0, 1, 0);
    stage(Ab, m0, 0, 0, 3, 0);
    VMW(2);
    BAR();

#define LDFRAG(base, row, kk) \
    (*(const s16x8*)((base) + (row) * 64 + ((((kk) * 4 + lk) ^ (lr & 7)) << 3)))

#define QUAD(mh, nh)                                                                   \
    __builtin_amdgcn_s_setprio(1);                                                     \
    _Pragma("unroll")                                                                  \
    for (int mf = 0; mf < 4; ++mf)                                                     \
        _Pragma("unroll")                                                              \
        for (int nf = 0; nf < 2; ++nf)                                                 \
            _Pragma("unroll")                                                          \
            for (int kk = 0; kk < 2; ++kk)                                             \
                acc[(mh) * 4 + mf][(nh) * 2 + nf] = __builtin_amdgcn_mfma_f32_16x16x32_bf16( \
                    a[mf][kk], b[(nh) * 2 + nf][kk], acc[(mh) * 4 + mf][(nh) * 2 + nf], 0, 0, 0); \
    __builtin_amdgcn_s_setprio(0);

    for (int kt = 0; kt < NT; ++kt) {
        const int buf = kt & 1;
        const u16* la = &lds[buf][0][0];
        const u16* lb = &lds[buf][1][0];
        const int nx = kt + 1;
        const bool st = nx < NT;

        // ---- phase 0: quadrant (0,0) ----
#pragma unroll
        for (int mf = 0; mf < 4; ++mf)
#pragma unroll
            for (int kk = 0; kk < 2; ++kk)
                a[mf][kk] = LDFRAG(la, wm * 128 + mf * 16 + lr, kk);
#pragma unroll
        for (int nf = 0; nf < 2; ++nf)
#pragma unroll
            for (int kk = 0; kk < 2; ++kk)
                b[nf][kk] = LDFRAG(lb, wn * 64 + nf * 16 + lr, kk);
        if (st) { stage(Bw, n0, 1, buf ^ 1, 0, nx); stage(Bw, n0, 1, buf ^ 1, 1, nx); }
        BAR();
        LGKM0();
        QUAD(0, 0);
        BAR();

        // ---- phase 1: quadrant (0,1) ----
#pragma unroll
        for (int nf = 2; nf < 4; ++nf)
#pragma unroll
            for (int kk = 0; kk < 2; ++kk)
                b[nf][kk] = LDFRAG(lb, wn * 64 + nf * 16 + lr, kk);
        if (st) { stage(Bw, n0, 1, buf ^ 1, 2, nx); stage(Bw, n0, 1, buf ^ 1, 3, nx); }
        BAR();
        LGKM0();
        QUAD(0, 1);
        if (kt == NT - 1) { VMW(0); } else { VMW(4); }   // current tile's A-upper landed
        BAR();

        // ---- phase 2: quadrant (1,0) ----
#pragma unroll
        for (int mf = 0; mf < 4; ++mf)
#pragma unroll
            for (int kk = 0; kk < 2; ++kk)
                a[mf][kk] = LDFRAG(la, wm * 128 + 64 + mf * 16 + lr, kk);
        if (st) { stage(Ab, m0, 0, buf ^ 1, 0, nx); stage(Ab, m0, 0, buf ^ 1, 2, nx); }
        BAR();
        LGKM0();
        QUAD(1, 0);
        BAR();

        // ---- phase 3: quadrant (1,1) ----
        if (st) { stage(Ab, m0, 0, buf ^ 1, 1, nx); stage(Ab, m0, 0, buf ^ 1, 3, nx); }
        BAR();
        QUAD(1, 1);
        VMW(2);   // next tile's first 6 quarters landed
        BAR();
    }

    // epilogue: C layout col = lr, row = lk*4 + reg
#pragma unroll
    for (int i = 0; i < 8; ++i)
#pragma unroll
        for (int j = 0; j < 4; ++j) {
            int r0 = m0 + wm * 128 + (i >> 2) * 64 + (i & 3) * 16 + lk * 4;
            int c0 = n0 + wn * 64 + j * 16 + lr;
            if constexpr (OUT_MODE == 1) {
                float* C = (float*)Cv;
#pragma unroll
                for (int r = 0; r < 4; ++r) C[(size_t)(r0 + r) * N + c0] = acc[i][j][r] * alpha;
            } else {
                u16* C = (u16*)Cv;
#pragma unroll
                for (int r = 0; r < 4; ++r) C[(size_t)(r0 + r) * N + c0] = f2b(acc[i][j][r] * alpha);
            }
        }
}

// ---------------- flash attention (round-14 winner, byte-identical) ----------------
__global__ __launch_bounds__(512, 2) void attn_kernel(
    const u16* __restrict__ Qh, const u16* __restrict__ Kh, const u16* __restrict__ Vh,
    const float* __restrict__ mask, const float* __restrict__ kpad,
    u16* __restrict__ Comb) {
    __shared__ u16 Ks[2][64 * 128];
    __shared__ u16 Vt[2][128 * 64];

    const int t = threadIdx.x, lane = t & 63, w = t >> 6;   // w: 0..7
    const int lr = lane & 15, lk = lane >> 4;

    const int g = blockIdx.x;
    const int rm = (g & 7) * 64 + (g >> 3);      // 512 % 8 == 0: bijective
    const int qb = rm & 7, h = (rm >> 3) & 15, b = rm >> 7;  // qb fast (L3-friendly)
    const int q0w = qb * 256 + w * 32;
    const size_t rowBase = (size_t)b * S_LEN;
    const u16* Kb = Kh + rowBase * D_MODEL + h * HD_DIM;
    const u16* Vb = Vh + rowBase * D_MODEL + h * HD_DIM;

    // Q fragments (B operand): q = q0w + qi*16 + lr, d = dc*32 + lk*8 + j.
    // (scale*log2e pre-folded into the Q projection)
    s16x8 qf[2][4];
#pragma unroll
    for (int qi = 0; qi < 2; ++qi)
#pragma unroll
        for (int dc = 0; dc < 4; ++dc)
            qf[qi][dc] = *(const s16x8*)(Qh + (rowBase + q0w + qi * 16 + lr) * D_MODEL +
                                         h * HD_DIM + dc * 32 + lk * 8);

    f32x4 o[2][8];
#pragma unroll
    for (int qi = 0; qi < 2; ++qi)
#pragma unroll
        for (int dt = 0; dt < 8; ++dt) o[qi][dt] = {0.f, 0.f, 0.f, 0.f};
    float m_[2] = {-3e38f, -3e38f}, l_[2] = {0.f, 0.f};

    // K staging (512 threads, 2 passes of 32 rows)
    const int ksub = t >> 4;                          // 0..31
    const int kchunk = (t & 15) ^ (ksub & 7);         // pre-swizzled global chunk
    // V staging (512 threads, one pass covers all 64 kv rows)
    const int vrow = t >> 3;                          // 0..63
    const int vc0 = (t & 7) * 16;
    const int vodd = vrow & 1;
    const int vp = t >> 4;                            // kv-pair 0..31

    s16x8 va0, va1;

    auto stageK = [&](int kv0, int nb) {
#pragma unroll
        for (int p = 0; p < 2; ++p) {
            const u16* src = Kb + (size_t)(kv0 + p * 32 + ksub) * D_MODEL + kchunk * 8;
            __builtin_amdgcn_global_load_lds(
                (const __attribute__((address_space(1))) void*)src,
                (__attribute__((address_space(3))) void*)(&Ks[nb][p * 4096 + t * 8]), 16, 0, 0);
        }
    };
    auto loadV = [&](int kv0) {
        const u16* p0 = Vb + (size_t)(kv0 + vrow) * D_MODEL + vc0;
        va0 = *(const s16x8*)p0;
        va1 = *(const s16x8*)(p0 + 8);
    };
    auto writeV = [&](int nb) {
        union VU { s16x8 v[2]; u32 uw[8]; u16 us[16]; };
        VU A;
        A.v[0] = va0; A.v[1] = va1;
        u32 ra[4];
#pragma unroll
        for (int i = 0; i < 4; ++i)
            ra[i] = (u32)__shfl_xor((int)(vodd ? A.uw[i] : A.uw[i + 4]), 8, 64);
#pragma unroll
        for (int e = 0; e < 8; ++e) {
            int d = vc0 + vodd * 8 + e;
            int swz = ((d >> 4) ^ (d & 7)) & 7;
            u16 rau = (u16)((ra[e >> 1] >> ((e & 1) * 16)) & 0xffff);
            u16 lo1, hi1;
            if (vodd) { lo1 = rau; hi1 = A.us[8 + e]; }
            else      { lo1 = A.us[e]; hi1 = rau; }
            int c1 = (vp >> 2) ^ swz;
            *(u32*)(&Vt[nb][d * 64 + c1 * 8 + (vp & 3) * 2]) = (u32)lo1 | ((u32)hi1 << 16);
        }
    };

    // mask/kpad register prefetch (one tile ahead)
    f32x4 mreg[2][4], kreg[4];
    auto loadMask = [&](int kv0) {
#pragma unroll
        for (int qi = 0; qi < 2; ++qi) {
            const float* mrow = mask + (size_t)(q0w + qi * 16 + lr) * S_LEN + kv0;
#pragma unroll
            for (int kt = 0; kt < 4; ++kt)
                mreg[qi][kt] = *(const f32x4*)(mrow + kt * 16 + lk * 4);
        }
#pragma unroll
        for (int kt = 0; kt < 4; ++kt)
            kreg[kt] = *(const f32x4*)(kpad + b * S_LEN + kv0 + kt * 16 + lk * 4);
    };

    // prologue: stage tile 0 (full drain once)
    stageK(0, 0);
    loadV(0);
    writeV(0);
    loadMask(0);
    __syncthreads();

    const int srcA = ((lk & 1) * 32) + lr;   // lane holding lk' = (lk&1)*2
    const int srcB = srcA + 16;

    for (int i = 0; i < 32; ++i) {
        const int cur = i & 1;
        const u16* ks = &Ks[cur][0];
        const u16* vt = &Vt[cur][0];
        const int kv0 = i * 64;

        if (i < 31) { stageK(kv0 + 64, cur ^ 1); loadV(kv0 + 64); }

        // QK^T (swapped): sc[qi][kt]: lane holds S[kv=kt*16+lk*4+r][q=qi*16+lr]
        f32x4 sc[2][4];
#pragma unroll
        for (int qi = 0; qi < 2; ++qi)
#pragma unroll
            for (int kt = 0; kt < 4; ++kt) sc[qi][kt] = {0.f, 0.f, 0.f, 0.f};
        __builtin_amdgcn_s_setprio(1);
#pragma unroll
        for (int kt = 0; kt < 4; ++kt) {
            s16x8 kf[4];
#pragma unroll
            for (int dc = 0; dc < 4; ++dc)
                kf[dc] = *(const s16x8*)(&ks[(kt * 16 + lr) * 128 +
                                             (((dc * 4 + lk) ^ (lr & 7)) << 3)]);
#pragma unroll
            for (int dc = 0; dc < 4; ++dc) {
                sc[0][kt] = __builtin_amdgcn_mfma_f32_16x16x32_bf16(kf[dc], qf[0][dc], sc[0][kt], 0, 0, 0);
                sc[1][kt] = __builtin_amdgcn_mfma_f32_16x16x32_bf16(kf[dc], qf[1][dc], sc[1][kt], 0, 0, 0);
            }
        }
        __builtin_amdgcn_s_setprio(0);

        // masks (prefetched regs, folded *log2e via fma) + online softmax (log2 domain)
        u32 lo[2][4], hi[2][4];
#pragma unroll
        for (int qi = 0; qi < 2; ++qi) {
            float s[16];
#pragma unroll
            for (int kt = 0; kt < 4; ++kt)
#pragma unroll
                for (int r = 0; r < 4; ++r)
                    s[kt * 4 + r] = fmaf(mreg[qi][kt][r], L2E,
                                         fmaf(kreg[kt][r], L2E, sc[qi][kt][r]));
            float t0 = max3a(s[0], s[1], s[2]);
            float t1 = max3a(s[3], s[4], s[5]);
            float t2 = max3a(s[6], s[7], s[8]);
            float t3 = max3a(s[9], s[10], s[11]);
            float t4 = max3a(s[12], s[13], s[14]);
            float mx = fmaxf(max3a(t0, t1, t2), max3a(t3, t4, s[15]));
            mx = fmaxf(mx, __shfl_xor(mx, 16, 64));
            mx = fmaxf(mx, __shfl_xor(mx, 32, 64));
            // defer-max (T13): 11.5 log2-units ~= 8 e-units
            if (__any(mx > m_[qi] + 11.5f)) {
                float mn = fmaxf(m_[qi], mx);
                float fs = exp2a(m_[qi] - mn);
                m_[qi] = mn;
                l_[qi] *= fs;
#pragma unroll
                for (int r = 0; r < 4; ++r) {
                    float fsb = __shfl(fs, (lane & 48) | (lk * 4 + r), 64);
#pragma unroll
                    for (int dt = 0; dt < 8; ++dt) o[qi][dt][r] *= fsb;
                }
            }
            float ls = 0.f;
#pragma unroll
            for (int e = 0; e < 16; ++e) { s[e] = exp2a(s[e] - m_[qi]); ls += s[e]; }
            ls += __shfl_xor(ls, 16, 64);
            ls += __shfl_xor(ls, 32, 64);
            l_[qi] += ls;
#pragma unroll
            for (int kt = 0; kt < 4; ++kt) {
                lo[qi][kt] = cvtpk(s[kt * 4 + 0], s[kt * 4 + 1]);
                hi[qi][kt] = cvtpk(s[kt * 4 + 2], s[kt * 4 + 3]);
            }
        }

        // prefetch next tile's mask/kpad (regs free after s[] computed above)
        if (i < 31) loadMask(kv0 + 64);

        // redistribute P (C-layout) -> A-frag in-register
        s16x8 pf[2][2];
        const bool sel = (lk >> 1) & 1;
#pragma unroll
        for (int qi = 0; qi < 2; ++qi)
#pragma unroll
            for (int hh = 0; hh < 2; ++hh) {
                u32 w0a = (u32)__shfl((int)lo[qi][2 * hh], srcA, 64);
                u32 w0b = (u32)__shfl((int)lo[qi][2 * hh + 1], srcA, 64);
                u32 w1a = (u32)__shfl((int)hi[qi][2 * hh], srcA, 64);
                u32 w1b = (u32)__shfl((int)hi[qi][2 * hh + 1], srcA, 64);
                u32 w2a = (u32)__shfl((int)lo[qi][2 * hh], srcB, 64);
                u32 w2b = (u32)__shfl((int)lo[qi][2 * hh + 1], srcB, 64);
                u32 w3a = (u32)__shfl((int)hi[qi][2 * hh], srcB, 64);
                u32 w3b = (u32)__shfl((int)hi[qi][2 * hh + 1], srcB, 64);
                union { s16x8 v; u32 u[4]; } P;
                P.u[0] = sel ? w0b : w0a;
                P.u[1] = sel ? w1b : w1a;
                P.u[2] = sel ? w2b : w2a;
                P.u[3] = sel ? w3b : w3a;
                pf[qi][hh] = P.v;
            }

        // PV: o[qi][dt] += P[16x64] @ V[64x16]
        __builtin_amdgcn_s_setprio(1);
#pragma unroll
        for (int dt = 0; dt < 8; ++dt) {
            int swz = dt ^ (lr & 7);
            s16x8 vf0 = *(const s16x8*)(&vt[(dt * 16 + lr) * 64 + ((lk ^ swz) << 3)]);
            s16x8 vf1 = *(const s16x8*)(&vt[(dt * 16 + lr) * 64 + (((4 + lk) ^ swz) << 3)]);
            o[0][dt] = __builtin_amdgcn_mfma_f32_16x16x32_bf16(pf[0][0], vf0, o[0][dt], 0, 0, 0);
            o[1][dt] = __builtin_amdgcn_mfma_f32_16x16x32_bf16(pf[1][0], vf0, o[1][dt], 0, 0, 0);
            o[0][dt] = __builtin_amdgcn_mfma_f32_16x16x32_bf16(pf[0][1], vf1, o[0][dt], 0, 0, 0);
            o[1][dt] = __builtin_amdgcn_mfma_f32_16x16x32_bf16(pf[1][1], vf1, o[1][dt], 0, 0, 0);
        }
        __builtin_amdgcn_s_setprio(0);

        if (i < 31) writeV(cur ^ 1);
        LGKM0();
        BAR();
    }

    // epilogue: O = o / l; o C-layout: q = qi*16 + lk*4 + r, d = dt*16 + lr
#pragma unroll
    for (int qi = 0; qi < 2; ++qi)
#pragma unroll
        for (int r = 0; r < 4; ++r) {
            float lb = __shfl(l_[qi], (lane & 48) | (lk * 4 + r), 64);
            float inv = 1.0f / lb;
            size_t row = rowBase + q0w + qi * 16 + lk * 4 + r;
            u16* dst = Comb + row * D_MODEL + h * HD_DIM + lr;
#pragma unroll
            for (int dt = 0; dt < 8; ++dt) dst[dt * 16] = f2b(o[qi][dt][r] * inv);
        }
}

extern "C" void kernel_launch(void* const* d_in, const int* in_sizes, int n_in,
                              void* d_out, int out_size, void* d_ws, size_t ws_size,
                              hipStream_t stream) {
    const float* q    = (const float*)d_in[0];
    const float* k    = (const float*)d_in[1];
    const float* v    = (const float*)d_in[2];
    const float* mask = (const float*)d_in[3];
    const float* kpad = (const float*)d_in[4];
    const float* wq   = (const float*)d_in[5];
    const float* wk   = (const float*)d_in[6];
    const float* wv   = (const float*)d_in[7];
    const float* wo   = (const float*)d_in[8];
    float* out = (float*)d_out;

    u16* wqb  = (u16*)d_ws;                 // 2048*2048 bf16 each, contiguous x4
    u16* wkb  = wqb + 4194304;
    u16* wvb  = wkb + 4194304;
    u16* wob  = wvb + 4194304;
    u16* qh   = wob + 4194304;              // 8192*2048 bf16 each
    u16* kh   = qh + 16777216;
    u16* vh   = kh + 16777216;
    u16* comb = vh + 16777216;
    // total: 160 MB

    // 1/sqrt(128) * log2(e): Q-projection alpha puts QK^T scores in log2 domain
    const float scale = 0.08838834764831845f * 1.4426950408889634f;

    // ONE conversion launch: weights -> wqb..wob; activations chained
    // q -> kh, k -> vh, v -> comb (each consumed exactly one GEMM before overwrite)
    {
        dim3 gc(8388608 / 256);
        cvt_all<<<gc, 256, 0, stream>>>(wq, wk, wv, wo, q, k, v, wqb, kh, vh, comb);
    }
    dim3 gg((8192 / 256) * (2048 / 256));   // 256 blocks

    gemm256<0><<<gg, 512, 0, stream>>>(kh,   wqb, qh, 8192, 2048, 2048, scale);  // Q proj
    gemm256<0><<<gg, 512, 0, stream>>>(vh,   wkb, kh, 8192, 2048, 2048, 1.0f);   // K proj
    gemm256<0><<<gg, 512, 0, stream>>>(comb, wvb, vh, 8192, 2048, 2048, 1.0f);   // V proj

    attn_kernel<<<dim3(512), 512, 0, stream>>>(qh, kh, vh, mask, kpad, comb);

    gemm256<1><<<gg, 512, 0, stream>>>(comb, wob, out, 8192, 2048, 2048, 1.0f);  // O proj
}